// Round 1
// baseline (2465.996 us; speedup 1.0000x reference)
//
#include <hip/hip_runtime.h>
#include <math.h>

#define BATCH 8
#define CH 256
#define NTOK 2304
#define TWO_C 512
#define TOPK 16
#define NCR 4        // column ranges per row (split across blocks)
#define CRW 576      // columns per range
#define BN 64        // rows per simtopk block
#define BM 64        // col tile inside a range
#define NTILES 9     // CRW / BM

// ---------- bf16 helpers (OCP bf16 bits, RNE) ----------
__device__ __forceinline__ unsigned short f32_to_bf16(float f) {
    unsigned int u = __float_as_uint(f);
    u += 0x7fffu + ((u >> 16) & 1u);
    return (unsigned short)(u >> 16);
}
__device__ __forceinline__ float bf16_to_f32(unsigned short h) {
    return __uint_as_float(((unsigned int)h) << 16);
}

// =======================================================================
// Kernel A: feat_pos = tokens @ W^T + bias
//   x:[B][C][N] (c-major => already K-major for A staging, no transpose)
//   feat (j<256) -> bf16 [B][N][256];  pos (j>=256) -> fp32 [B][N][256]
//   block: 64 rows x 128 cols, 256 thr, thread tile 4x8
// =======================================================================
__global__ __launch_bounds__(256) void k_gemm1(const float* __restrict__ x,
                                               const float* __restrict__ Wm,
                                               const float* __restrict__ bias,
                                               unsigned short* __restrict__ feat,
                                               float* __restrict__ pos) {
    __shared__ float As[32 * 64];    // [kk][n]
    __shared__ float Bs[32 * 128];   // [kk][j]
    const int jb = blockIdx.x;       // 0..3
    const int nb = blockIdx.y;       // 0..35
    const int b  = blockIdx.z;
    const int tid = threadIdx.x;
    const int rg = tid >> 4;         // 16 row-groups * 4 rows
    const int cg = tid & 15;         // 16 col-groups * 8 cols
    const int n0 = nb * 64;
    const int j0 = jb * 128;
    const float* xb = x + (size_t)b * CH * NTOK;

    float acc[4][8];
    #pragma unroll
    for (int i = 0; i < 4; ++i)
        #pragma unroll
        for (int j = 0; j < 8; ++j) acc[i][j] = 0.f;

    for (int c0 = 0; c0 < CH; c0 += 32) {
        __syncthreads();
        // stage As[kk][r] = x[b][c0+kk][n0+r]  (direct copy, coalesced 256B/row)
        #pragma unroll
        for (int it = 0; it < 2; ++it) {
            const int task = tid + it * 256;
            const int kk = task >> 4;
            const int part = task & 15;
            const float4 v = *reinterpret_cast<const float4*>(
                xb + (size_t)(c0 + kk) * NTOK + n0 + part * 4);
            *reinterpret_cast<float4*>(&As[kk * 64 + part * 4]) = v;
        }
        // stage Bs[kk][j] = W[j0+j][c0+kk]  (transpose in LDS store)
        #pragma unroll
        for (int it = 0; it < 4; ++it) {
            const int task = tid + it * 256;
            const int qd = task & 7;
            const int j = task >> 3;
            const float4 v = *reinterpret_cast<const float4*>(
                Wm + (size_t)(j0 + j) * CH + c0 + qd * 4);
            Bs[(qd * 4 + 0) * 128 + j] = v.x;
            Bs[(qd * 4 + 1) * 128 + j] = v.y;
            Bs[(qd * 4 + 2) * 128 + j] = v.z;
            Bs[(qd * 4 + 3) * 128 + j] = v.w;
        }
        __syncthreads();
        #pragma unroll
        for (int kk = 0; kk < 32; ++kk) {
            const float4 a  = *reinterpret_cast<const float4*>(&As[kk * 64 + rg * 4]);
            const float4 b0 = *reinterpret_cast<const float4*>(&Bs[kk * 128 + cg * 8]);
            const float4 b1 = *reinterpret_cast<const float4*>(&Bs[kk * 128 + cg * 8 + 4]);
            const float av[4] = {a.x, a.y, a.z, a.w};
            const float bv[8] = {b0.x, b0.y, b0.z, b0.w, b1.x, b1.y, b1.z, b1.w};
            #pragma unroll
            for (int i = 0; i < 4; ++i)
                #pragma unroll
                for (int j = 0; j < 8; ++j)
                    acc[i][j] = fmaf(av[i], bv[j], acc[i][j]);
        }
    }
    float bj[8];
    #pragma unroll
    for (int j = 0; j < 8; ++j) bj[j] = bias[j0 + cg * 8 + j];
    #pragma unroll
    for (int i = 0; i < 4; ++i) {
        const size_t row = (size_t)b * NTOK + n0 + rg * 4 + i;
        if (j0 < 256) {
            unsigned short us[8];
            #pragma unroll
            for (int j = 0; j < 8; ++j) us[j] = f32_to_bf16(acc[i][j] + bj[j]);
            uint4 o;
            o.x = (unsigned)us[0] | ((unsigned)us[1] << 16);
            o.y = (unsigned)us[2] | ((unsigned)us[3] << 16);
            o.z = (unsigned)us[4] | ((unsigned)us[5] << 16);
            o.w = (unsigned)us[6] | ((unsigned)us[7] << 16);
            *reinterpret_cast<uint4*>(feat + row * CH + j0 + cg * 8) = o;
        } else {
            const float4 o0 = make_float4(acc[i][0] + bj[0], acc[i][1] + bj[1],
                                          acc[i][2] + bj[2], acc[i][3] + bj[3]);
            const float4 o1 = make_float4(acc[i][4] + bj[4], acc[i][5] + bj[5],
                                          acc[i][6] + bj[6], acc[i][7] + bj[7]);
            float* dst = pos + row * CH + (j0 - 256) + cg * 8;
            *reinterpret_cast<float4*>(dst) = o0;
            *reinterpret_cast<float4*>(dst + 4) = o1;
        }
    }
}

// =======================================================================
// Kernel A2: L2-normalize each pos row (one wave per row)
// =======================================================================
__global__ __launch_bounds__(256) void k_norm(float* __restrict__ pos) {
    const int tid = threadIdx.x;
    const int lane = tid & 63;
    const int wv = tid >> 6;
    const size_t row = (size_t)blockIdx.x * 4 + wv;
    float* p = pos + row * CH + lane * 4;
    float4 v = *reinterpret_cast<const float4*>(p);
    float ss = v.x * v.x + v.y * v.y + v.z * v.z + v.w * v.w;
    #pragma unroll
    for (int off = 1; off < 64; off <<= 1) ss += __shfl_xor(ss, off);
    const float m = fmaxf(sqrtf(ss), 1e-12f);
    v.x /= m; v.y /= m; v.z /= m; v.w /= m;
    *reinterpret_cast<float4*>(p) = v;
}

// =======================================================================
// Kernel B: fused sim-GEMM + streaming top-16 (fp32, never materialize sim)
//   grid (cr, nb, b) = (4, 36, 8); 64 rows x 576 cols per block
//   per row: 4 sub-threads each keep a private top-16 in LDS
// =======================================================================
__global__ __launch_bounds__(256) void k_simtopk(const float* __restrict__ pos,
                                                 float* __restrict__ pv,
                                                 int* __restrict__ pi) {
    // overlay: AsT[256][64]=16384f | region max(Bs[32][64]=2048f, sim[64][65]=4160f)
    //          topv[16][256]=4096f | topi[16][256]u16=2048f   => 26688f = 104.3 KB
    __shared__ float smem[26688];
    float* AsT  = smem;                  // [k][r]
    float* Bs   = smem + 16384;          // [kk][c]
    float* simt = smem + 16384;          // [64][65] (overlays Bs)
    float* topv = smem + 20544;          // [slot][tid]
    unsigned short* topi = reinterpret_cast<unsigned short*>(smem + 24640);

    const int cr = blockIdx.x;
    const int nb = blockIdx.y;
    const int b  = blockIdx.z;
    const int tid = threadIdx.x;
    const int rg = tid >> 4;             // 16 row-groups * 4
    const int cg = tid & 15;             // 16 col-groups * 4
    const int n0 = nb * BN;
    const float* posb = pos + (size_t)b * NTOK * CH;
    const float* posA = posb + (size_t)n0 * CH;

    // stage AsT[k][r] = pos[n0+r][k]  (coalesced 1KB/row reads)
    #pragma unroll
    for (int it = 0; it < 16; ++it) {
        const int task = tid + it * 256;
        const int quad = task & 63;
        const int row = task >> 6;
        const float4 v = *reinterpret_cast<const float4*>(posA + (size_t)row * CH + quad * 4);
        AsT[(quad * 4 + 0) * 64 + row] = v.x;
        AsT[(quad * 4 + 1) * 64 + row] = v.y;
        AsT[(quad * 4 + 2) * 64 + row] = v.z;
        AsT[(quad * 4 + 3) * 64 + row] = v.w;
    }
    #pragma unroll
    for (int s = 0; s < 16; ++s) {
        topv[s * 256 + tid] = -3.0e38f;
        topi[s * 256 + tid] = (unsigned short)0xffffu;
    }
    float curmin = -3.0e38f;
    int minslot = 0;
    const int srow = tid >> 2;
    const int ssub = tid & 3;

    for (int mt = 0; mt < NTILES; ++mt) {
        const int m0 = cr * CRW + mt * BM;
        float acc[4][4];
        #pragma unroll
        for (int i = 0; i < 4; ++i)
            #pragma unroll
            for (int j = 0; j < 4; ++j) acc[i][j] = 0.f;
        for (int c0 = 0; c0 < CH; c0 += 32) {
            __syncthreads();   // also protects simt readers from Bs overwrite
            #pragma unroll
            for (int it = 0; it < 2; ++it) {
                const int task = tid + it * 256;
                const int qd = task & 7;
                const int c = task >> 3;
                const float4 v = *reinterpret_cast<const float4*>(
                    posb + (size_t)(m0 + c) * CH + c0 + qd * 4);
                Bs[(qd * 4 + 0) * 64 + c] = v.x;
                Bs[(qd * 4 + 1) * 64 + c] = v.y;
                Bs[(qd * 4 + 2) * 64 + c] = v.z;
                Bs[(qd * 4 + 3) * 64 + c] = v.w;
            }
            __syncthreads();
            #pragma unroll
            for (int kk = 0; kk < 32; ++kk) {
                const float4 a  = *reinterpret_cast<const float4*>(&AsT[(c0 + kk) * 64 + rg * 4]);
                const float4 bv = *reinterpret_cast<const float4*>(&Bs[kk * 64 + cg * 4]);
                const float av[4] = {a.x, a.y, a.z, a.w};
                const float bb[4] = {bv.x, bv.y, bv.z, bv.w};
                #pragma unroll
                for (int i = 0; i < 4; ++i)
                    #pragma unroll
                    for (int j = 0; j < 4; ++j)
                        acc[i][j] = fmaf(av[i], bb[j], acc[i][j]);
            }
        }
        __syncthreads();       // all FMA done reading Bs region
        #pragma unroll
        for (int i = 0; i < 4; ++i)
            #pragma unroll
            for (int j = 0; j < 4; ++j)
                simt[(rg * 4 + i) * 65 + cg * 4 + j] = acc[i][j];
        __syncthreads();
        // scan: row = tid>>2, 4 sub-threads own 16 contiguous cols each
        const int gbase = m0 + ssub * 16;
        const int lbase = srow * 65 + ssub * 16;
        #pragma unroll
        for (int i = 0; i < 16; ++i) {
            const float v = simt[lbase + i];
            if (v > curmin) {   // ties keep existing (lower idx: ascending stream)
                topv[minslot * 256 + tid] = v;
                topi[minslot * 256 + tid] = (unsigned short)(gbase + i);
                float nm = 3.0e38f;
                int ns = 0;
                int nid = -1;
                #pragma unroll
                for (int s = 0; s < 16; ++s) {
                    const float tv = topv[s * 256 + tid];
                    const int ti = (int)topi[s * 256 + tid];
                    // min value; among ties evict the LARGER index first
                    if (tv < nm || (tv == nm && ti > nid)) { nm = tv; ns = s; nid = ti; }
                }
                curmin = nm;
                minslot = ns;
            }
        }
    }
    // dump per-thread partial top-16
    const size_t n = (size_t)b * NTOK + n0 + srow;
    float* dv = pv + (((size_t)n * NCR + cr) * 4 + ssub) * 16;
    int* di = pi + (((size_t)n * NCR + cr) * 4 + ssub) * 16;
    #pragma unroll
    for (int s = 0; s < 16; ++s) {
        dv[s] = topv[s * 256 + tid];
        di[s] = (int)topi[s * 256 + tid];
    }
}

// =======================================================================
// Kernel B2: merge 16 partial lists (4 cr x 4 sub) of 16 -> exact top-16
//   64 rows per block; jax top_k tie semantics (equal value -> lower index)
// =======================================================================
__global__ __launch_bounds__(256) void k_merge(const float* __restrict__ pv,
                                               const int* __restrict__ pi,
                                               float* __restrict__ tkv,
                                               int* __restrict__ tki) {
    __shared__ float mv[64 * 257];   // 64 rows x 256 candidates (+1 pad)
    __shared__ int mi[64 * 257];
    const int tid = threadIdx.x;
    const int row = tid >> 2;
    const int sub = tid & 3;        // loads 64 of the 256 candidates
    const size_t gr = (size_t)blockIdx.x * 64 + row;
    #pragma unroll
    for (int q = 0; q < 16; ++q) {
        const float4 v = *reinterpret_cast<const float4*>(pv + (gr * 256) + sub * 64 + q * 4);
        const int4 ii = *reinterpret_cast<const int4*>(pi + (gr * 256) + sub * 64 + q * 4);
        const int base = row * 257 + sub * 64 + q * 4;
        mv[base + 0] = v.x; mv[base + 1] = v.y; mv[base + 2] = v.z; mv[base + 3] = v.w;
        mi[base + 0] = ii.x; mi[base + 1] = ii.y; mi[base + 2] = ii.z; mi[base + 3] = ii.w;
    }
    __syncthreads();
    if (tid < 64) {
        const size_t n = (size_t)blockIdx.x * 64 + tid;
        float* ov = tkv + n * 16;
        int* oi = tki + n * 16;
        const int rb = tid * 257;
        for (int k = 0; k < 16; ++k) {
            float best = -3.0e38f;
            int bidx = 0x7fffffff;
            int bslot = 0;
            for (int c = 0; c < 256; ++c) {
                const float v = mv[rb + c];
                const int id = mi[rb + c];
                if (v > best || (v == best && id < bidx)) { best = v; bidx = id; bslot = c; }
            }
            mv[rb + bslot] = -3.0e38f;
            ov[k] = best;
            oi[k] = bidx;
        }
    }
}

// =======================================================================
// Kernel C: softmax over top-16 + gather feat + weighted sum, transpose-store
//   out[b][c][n]; 32 rows per block, staged through padded LDS tile
// =======================================================================
__global__ __launch_bounds__(256) void k_out(const unsigned short* __restrict__ feat,
                                             const float* __restrict__ tkv,
                                             const int* __restrict__ tki,
                                             float* __restrict__ out) {
    __shared__ float wts[32][16];
    __shared__ int ids[32][16];
    __shared__ float tmp[32][257];
    const int nb = blockIdx.x;
    const int b = blockIdx.y;
    const int n0 = nb * 32;
    const int tid = threadIdx.x;
    if (tid < 32) {
        const size_t n = (size_t)b * NTOK + n0 + tid;
        const float* v = tkv + n * 16;
        const int* id = tki + n * 16;
        float mx = v[0];
        #pragma unroll
        for (int k = 1; k < 16; ++k) mx = fmaxf(mx, v[k]);
        float e[16];
        float s = 0.f;
        #pragma unroll
        for (int k = 0; k < 16; ++k) { e[k] = expf(v[k] - mx); s += e[k]; }
        const float inv = 1.0f / s;
        #pragma unroll
        for (int k = 0; k < 16; ++k) { wts[tid][k] = e[k] * inv; ids[tid][k] = id[k]; }
    }
    __syncthreads();
    const unsigned short* featb = feat + (size_t)b * NTOK * CH;
    const int c = tid;
    for (int n = 0; n < 32; ++n) {
        float a = 0.f;
        #pragma unroll
        for (int k = 0; k < 16; ++k)
            a = fmaf(wts[n][k], bf16_to_f32(featb[(size_t)ids[n][k] * CH + c]), a);
        tmp[n][c] = a;
    }
    __syncthreads();
    float* outb = out + (size_t)b * CH * NTOK + n0;
    #pragma unroll
    for (int ci = 0; ci < 32; ++ci) {
        const int cc = ci * 8 + (tid >> 5);
        const int nn = tid & 31;
        outb[(size_t)cc * NTOK + nn] = tmp[nn][cc];
    }
}

// =======================================================================
extern "C" void kernel_launch(void* const* d_in, const int* in_sizes, int n_in,
                              void* d_out, int out_size, void* d_ws, size_t ws_size,
                              hipStream_t stream) {
    (void)in_sizes; (void)n_in; (void)out_size; (void)ws_size;
    const float* x    = (const float*)d_in[0];
    const float* Wm   = (const float*)d_in[1];
    const float* bias = (const float*)d_in[2];
    float* out = (float*)d_out;

    char* ws = (char*)d_ws;
    // ws layout (bytes):
    //  pos   fp32 [8][2304][256]            18,874,368
    //  feat  bf16 [8][2304][256]             9,437,184
    //  pv    f32  [8][2304][4cr][4sub][16]  18,874,368
    //  pi    i32  same                      18,874,368
    //  tkv   f32  [8][2304][16]              1,179,648
    //  tki   i32  [8][2304][16]              1,179,648
    float* pos = (float*)ws;
    unsigned short* feat = (unsigned short*)(ws + 18874368);
    float* pv = (float*)(ws + 18874368 + 9437184);
    int* pi = (int*)(ws + 18874368 + 9437184 + 18874368);
    float* tkv = (float*)(ws + 18874368 + 9437184 + 18874368 + 18874368);
    int* tki = (int*)(ws + 18874368 + 9437184 + 18874368 + 18874368 + 1179648);

    k_gemm1<<<dim3(4, 36, 8), 256, 0, stream>>>(x, Wm, bias, feat, pos);
    k_norm<<<dim3(4608), 256, 0, stream>>>(pos);
    k_simtopk<<<dim3(NCR, 36, 8), 256, 0, stream>>>(pos, pv, pi);
    k_merge<<<dim3(288), 256, 0, stream>>>(pv, pi, tkv, tki);
    k_out<<<dim3(72, 8), 256, 0, stream>>>(feat, tkv, tki, out);
}

// Round 9
// 434.545 us; speedup vs baseline: 5.6749x; 5.6749x over previous
//
#include <hip/hip_runtime.h>
#include <math.h>

#define CH 256
#define NTOK 2304
#define TOPK 16
#define RK 24       // candidate-set size per row (superset margin: needs >=9 bf16 flips to fail)
#define CAP 96      // LDS candidate buffer capacity (bound: 63+32=95 <= 96)
#define CAPS 97     // padded stride (bank spread)

typedef __attribute__((ext_vector_type(8))) short short8;
typedef __attribute__((ext_vector_type(4))) float f32x4;

// ---------- bf16 helpers (OCP bf16 bits, RNE) ----------
__device__ __forceinline__ unsigned short f32_to_bf16(float f) {
    unsigned int u = __float_as_uint(f);
    u += 0x7fffu + ((u >> 16) & 1u);
    return (unsigned short)(u >> 16);
}
__device__ __forceinline__ float bf16_to_f32(unsigned short h) {
    return __uint_as_float(((unsigned int)h) << 16);
}

// =======================================================================
// Kernel W: transpose W [512][256] -> Wt [256][512] (one-off, tiny)
// =======================================================================
__global__ __launch_bounds__(256) void k_wt(const float* __restrict__ W,
                                            float* __restrict__ Wt) {
    __shared__ float t[32][33];
    const int bx = blockIdx.x;  // col tile (256/32 = 8)
    const int by = blockIdx.y;  // row tile (512/32 = 16)
    const int tid = threadIdx.x;
    {
        const int r = tid >> 3, c4 = tid & 7;
        const float4 v = *reinterpret_cast<const float4*>(
            W + (size_t)(by * 32 + r) * 256 + bx * 32 + c4 * 4);
        t[r][c4 * 4 + 0] = v.x; t[r][c4 * 4 + 1] = v.y;
        t[r][c4 * 4 + 2] = v.z; t[r][c4 * 4 + 3] = v.w;
    }
    __syncthreads();
    {
        const int c = tid >> 3, r4 = tid & 7;
        float4 o;
        o.x = t[r4 * 4 + 0][c]; o.y = t[r4 * 4 + 1][c];
        o.z = t[r4 * 4 + 2][c]; o.w = t[r4 * 4 + 3][c];
        *reinterpret_cast<float4*>(Wt + (size_t)(bx * 32 + c) * 512 + by * 32 + r4 * 4) = o;
    }
}

// =======================================================================
// Kernel A: feat_pos = tokens @ W^T + bias  (fp32 vector GEMM)
//   x:[B][C][N] (k-major), Wt:[C][512] (k-major) -> both staged linear.
//   feat (j<256) -> bf16 [B][N][256];  pos (j>=256) -> fp32 [B][N][256]
//   NOTE: ascending-k sequential fmaf chain — k_rescore replicates it.
// =======================================================================
__global__ __launch_bounds__(256) void k_gemm1(const float* __restrict__ x,
                                               const float* __restrict__ Wt,
                                               const float* __restrict__ bias,
                                               unsigned short* __restrict__ feat,
                                               float* __restrict__ pos) {
    __shared__ float As[32 * 64];    // [kk][n]
    __shared__ float Bs[32 * 128];   // [kk][j]
    const int jb = blockIdx.x;       // 0..3
    const int nb = blockIdx.y;       // 0..35
    const int b  = blockIdx.z;
    const int tid = threadIdx.x;
    const int rg = tid >> 4;         // 16 row-groups * 4 rows
    const int cg = tid & 15;         // 16 col-groups * 8 cols
    const int n0 = nb * 64;
    const int j0 = jb * 128;
    const float* xb = x + (size_t)b * CH * NTOK;

    float acc[4][8];
    #pragma unroll
    for (int i = 0; i < 4; ++i)
        #pragma unroll
        for (int j = 0; j < 8; ++j) acc[i][j] = 0.f;

    for (int c0 = 0; c0 < CH; c0 += 32) {
        __syncthreads();
        // stage As[kk][r] = x[b][c0+kk][n0+r]  (direct copy, linear LDS writes)
        #pragma unroll
        for (int it = 0; it < 2; ++it) {
            const int task = tid + it * 256;
            const int kk = task >> 4;
            const int part = task & 15;
            *reinterpret_cast<float4*>(&As[kk * 64 + part * 4]) =
                *reinterpret_cast<const float4*>(xb + (size_t)(c0 + kk) * NTOK + n0 + part * 4);
        }
        // stage Bs[kk][j] = Wt[c0+kk][j0+j]  (direct copy, linear LDS writes)
        #pragma unroll
        for (int it = 0; it < 4; ++it) {
            const int task = tid + it * 256;
            const int kk = task >> 5;
            const int f4 = task & 31;
            *reinterpret_cast<float4*>(&Bs[kk * 128 + f4 * 4]) =
                *reinterpret_cast<const float4*>(Wt + (size_t)(c0 + kk) * 512 + j0 + f4 * 4);
        }
        __syncthreads();
        #pragma unroll
        for (int kk = 0; kk < 32; ++kk) {
            const float4 a  = *reinterpret_cast<const float4*>(&As[kk * 64 + rg * 4]);
            const float4 b0 = *reinterpret_cast<const float4*>(&Bs[kk * 128 + cg * 8]);
            const float4 b1 = *reinterpret_cast<const float4*>(&Bs[kk * 128 + cg * 8 + 4]);
            const float av[4] = {a.x, a.y, a.z, a.w};
            const float bv[8] = {b0.x, b0.y, b0.z, b0.w, b1.x, b1.y, b1.z, b1.w};
            #pragma unroll
            for (int i = 0; i < 4; ++i)
                #pragma unroll
                for (int j = 0; j < 8; ++j)
                    acc[i][j] = fmaf(av[i], bv[j], acc[i][j]);
        }
    }
    float bj[8];
    #pragma unroll
    for (int j = 0; j < 8; ++j) bj[j] = bias[j0 + cg * 8 + j];
    #pragma unroll
    for (int i = 0; i < 4; ++i) {
        const size_t row = (size_t)b * NTOK + n0 + rg * 4 + i;
        if (j0 < 256) {
            unsigned short us[8];
            #pragma unroll
            for (int j = 0; j < 8; ++j) us[j] = f32_to_bf16(acc[i][j] + bj[j]);
            uint4 o;
            o.x = (unsigned)us[0] | ((unsigned)us[1] << 16);
            o.y = (unsigned)us[2] | ((unsigned)us[3] << 16);
            o.z = (unsigned)us[4] | ((unsigned)us[5] << 16);
            o.w = (unsigned)us[6] | ((unsigned)us[7] << 16);
            *reinterpret_cast<uint4*>(feat + row * CH + j0 + cg * 8) = o;
        } else {
            const float4 o0 = make_float4(acc[i][0] + bj[0], acc[i][1] + bj[1],
                                          acc[i][2] + bj[2], acc[i][3] + bj[3]);
            const float4 o1 = make_float4(acc[i][4] + bj[4], acc[i][5] + bj[5],
                                          acc[i][6] + bj[6], acc[i][7] + bj[7]);
            float* dst = pos + row * CH + (j0 - 256) + cg * 8;
            *reinterpret_cast<float4*>(dst) = o0;
            *reinterpret_cast<float4*>(dst + 4) = o1;
        }
    }
}

// =======================================================================
// Kernel A2: L2-normalize pos rows (fp32 in place) + emit bf16 copy
// =======================================================================
__global__ __launch_bounds__(256) void k_norm(float* __restrict__ pos,
                                              unsigned short* __restrict__ posbf) {
    const int tid = threadIdx.x;
    const int lane = tid & 63;
    const int wv = tid >> 6;
    const size_t row = (size_t)blockIdx.x * 4 + wv;
    float* p = pos + row * CH + lane * 4;
    float4 v = *reinterpret_cast<const float4*>(p);
    float ss = v.x * v.x + v.y * v.y + v.z * v.z + v.w * v.w;
    #pragma unroll
    for (int off = 1; off < 64; off <<= 1) ss += __shfl_xor(ss, off);
    const float m = fmaxf(sqrtf(ss), 1e-12f);
    v.x /= m; v.y /= m; v.z /= m; v.w /= m;
    *reinterpret_cast<float4*>(p) = v;
    ushort4 h;
    h.x = f32_to_bf16(v.x); h.y = f32_to_bf16(v.y);
    h.z = f32_to_bf16(v.z); h.w = f32_to_bf16(v.w);
    *reinterpret_cast<ushort4*>(posbf + row * CH + lane * 4) = h;
}

// =======================================================================
// Kernel B: bf16-MFMA sim + threshold-filtered candidate top-24 per row
//   Block: 32 rows x all 2304 keys. 4 waves: (rt,kt) quadrants of 32x32.
//   A-fragments register-resident; B tiles (32 keys) double-buffered,
//   XOR-swizzled [key][k] layout (conflict-free ds_read_b128).
// =======================================================================
__device__ __forceinline__ void maintain(unsigned int* cbuf, int* ccnt,
                                         unsigned int* cthresh, int* mflag,
                                         int row, int sub, int tid) {
    int m = ccnt[row]; if (m > CAP) m = CAP;
    unsigned int pk[12]; int rk[12];
    #pragma unroll
    for (int k = 0; k < 12; ++k) {
        const int slot = sub + (k << 3);
        pk[k] = (slot < m) ? cbuf[row * CAPS + slot] : 0u;
        rk[k] = 0;
    }
    for (int j = 0; j < m; ++j) {
        const unsigned int pv = cbuf[row * CAPS + j];
        #pragma unroll
        for (int k = 0; k < 12; ++k) rk[k] += (pv > pk[k]) ? 1 : 0;
    }
    __syncthreads();
    if (tid == 0) *mflag = 0;
    #pragma unroll
    for (int k = 0; k < 12; ++k) {
        const int slot = sub + (k << 3);
        if (slot < m && rk[k] < RK) cbuf[row * CAPS + rk[k]] = pk[k];
        if (slot < m && rk[k] == RK - 1) cthresh[row] = pk[k];
    }
    if (sub == 0) ccnt[row] = (m < RK) ? m : RK;
    __syncthreads();
}

__global__ __launch_bounds__(256) void k_simsel(const unsigned short* __restrict__ posbf,
                                                int* __restrict__ cand) {
    __shared__ uint4 Bbuf[2][32 * 32];             // 2 x 32 keys x 512B
    __shared__ __align__(16) float simt[32 * 36];  // [row][col] padded
    __shared__ unsigned int cbuf[32 * CAPS];
    __shared__ int ccnt[32];
    __shared__ unsigned int cthresh[32];
    __shared__ int mflag;

    const int tid = threadIdx.x;
    const int lane = tid & 63;
    const int wv = tid >> 6;
    const int rt = wv & 1;          // row-tile 0/1
    const int kt = wv >> 1;         // key-tile 0/1
    const int grp = lane >> 4;      // 0..3
    const int l15 = lane & 15;
    const int nb = blockIdx.x;      // 0..71
    const int b  = blockIdx.y;
    const int rbase = nb * 32;
    const unsigned short* pb = posbf + (size_t)b * NTOK * CH;

    // A fragments: 16 rows (this wave's rt tile), full K=256 in regs (32 VGPR)
    const unsigned short* aptr = pb + (size_t)(rbase + rt * 16 + l15) * CH;
    short8 afr[8];
    #pragma unroll
    for (int ks = 0; ks < 8; ++ks)
        afr[ks] = *reinterpret_cast<const short8*>(aptr + ks * 32 + grp * 8);

    if (tid < 32) { ccnt[tid] = 0; cthresh[tid] = 0u; }
    if (tid == 0) mflag = 0;

    // staging mapping: thread -> (key, 4 consecutive 16B units), swizzled LDS writes
    const int skey = tid >> 3;        // 0..31
    const int sk7 = skey & 7;
    const int sm0 = (tid & 7) * 4;    // unit base (0..28)
    {
        const uint4* g = reinterpret_cast<const uint4*>(pb + (size_t)skey * CH);
        #pragma unroll
        for (int i = 0; i < 4; ++i)
            Bbuf[0][skey * 32 + ((sm0 + i) ^ sk7)] = g[sm0 + i];
    }
    __syncthreads();

    const int srow = tid >> 3;        // scan row 0..31
    const int ssub = tid & 7;         // scan sub 0..7 (4 cols each)
    const int keyl = kt * 16 + l15;   // MFMA B key (local)
    const int k7 = keyl & 7;
    int cur = 0;

    for (int s = 0; s < 72; ++s) {
        if (mflag) maintain(cbuf, ccnt, cthresh, &mflag, srow, ssub, tid);
        // issue next-chunk global loads early (land under MFMA)
        uint4 rg0, rg1, rg2, rg3;
        const bool have_next = (s + 1 < 72);
        if (have_next) {
            const uint4* g = reinterpret_cast<const uint4*>(
                pb + (size_t)((s + 1) * 32 + skey) * CH);
            rg0 = g[sm0 + 0]; rg1 = g[sm0 + 1]; rg2 = g[sm0 + 2]; rg3 = g[sm0 + 3];
        }
        // MFMA: this wave's 16x16 quadrant over K=256
        f32x4 acc = {0.f, 0.f, 0.f, 0.f};
        #pragma unroll
        for (int ks = 0; ks < 8; ++ks) {
            const short8 bf = *reinterpret_cast<const short8*>(
                &Bbuf[cur][keyl * 32 + ((ks * 4 + grp) ^ k7)]);
            acc = __builtin_amdgcn_mfma_f32_16x16x32_bf16(afr[ks], bf, acc, 0, 0, 0);
        }
        // dump sims (C layout: col=lane&15, row=(lane>>4)*4+r)
        {
            const int row_l = rt * 16 + grp * 4;
            const int col_l = kt * 16 + l15;
            #pragma unroll
            for (int r = 0; r < 4; ++r) simt[(row_l + r) * 36 + col_l] = acc[r];
        }
        // write staged next-B (vmcnt wait here, hidden under MFMA)
        if (have_next) {
            Bbuf[cur ^ 1][skey * 32 + ((sm0 + 0) ^ sk7)] = rg0;
            Bbuf[cur ^ 1][skey * 32 + ((sm0 + 1) ^ sk7)] = rg1;
            Bbuf[cur ^ 1][skey * 32 + ((sm0 + 2) ^ sk7)] = rg2;
            Bbuf[cur ^ 1][skey * 32 + ((sm0 + 3) ^ sk7)] = rg3;
        }
        __syncthreads();
        // scan: threshold filter + atomic append of packed (val20|idx12)
        {
            const float4 sv = *reinterpret_cast<const float4*>(&simt[srow * 36 + ssub * 4]);
            const unsigned int th = cthresh[srow];
            const int colg = s * 32 + ssub * 4;
            const float vv[4] = {sv.x, sv.y, sv.z, sv.w};
            #pragma unroll
            for (int i = 0; i < 4; ++i) {
                const unsigned int u = __float_as_uint(vv[i]);
                const unsigned int so = u ^ (0x80000000u | (unsigned int)((int)u >> 31));
                const unsigned int pack = (so & 0xFFFFF000u) | (unsigned int)(2303 - (colg + i));
                if (pack > th) {
                    const int slot = atomicAdd(&ccnt[srow], 1);
                    if (slot < CAP) cbuf[srow * CAPS + slot] = pack;
                }
            }
        }
        // barrier so the flag check reads a STABLE ccnt (race fix: a stale
        // read could defer maintain one step and overflow CAP -> lost cands)
        __syncthreads();
        if (ssub == 0 && ccnt[srow] >= 64) mflag = 1;
        __syncthreads();
        cur ^= 1;
    }
    maintain(cbuf, ccnt, cthresh, &mflag, srow, ssub, tid);
    // write candidate sets (rank-ordered top-24 in slots 0..23)
    const size_t rowg = (size_t)b * NTOK + rbase + srow;
    for (int k = ssub; k < RK; k += 8)
        cand[rowg * RK + k] = 2303 - (int)(cbuf[srow * CAPS + k] & 0xFFFu);
}

// =======================================================================
// Kernel C: fp32 exact rescore of 24 candidates -> top-16 + softmax
//   1 wave per row; lane = candidate; the dot is a SEQUENTIAL ascending-k
//   fmaf chain, bit-identical to round-1's validated accumulation order.
//   Reference tie semantics (value desc, index asc).
// =======================================================================
__global__ __launch_bounds__(256) void k_rescore(const float* __restrict__ pos,
                                                 const int* __restrict__ cand,
                                                 float* __restrict__ wsoft,
                                                 int* __restrict__ widx) {
    const int tid = threadIdx.x;
    const int lane = tid & 63;
    const int wv = tid >> 6;
    const int row = blockIdx.x * 4 + wv;         // 0..18431
    const int b = row / NTOK;
    const int rloc = row - b * NTOK;
    const float* posb = pos + (size_t)b * NTOK * CH;
    const float* qrow = posb + (size_t)rloc * CH;

    const int cidx = (lane < RK) ? cand[(size_t)row * RK + lane] : 0;
    const float* krow = posb + (size_t)cidx * CH;

    // sequential ascending-k fma chain (DO NOT reassociate: selection
    // correctness depends on bit-matching round-1's summation order)
    float acc = 0.f;
    #pragma unroll 8
    for (int k4 = 0; k4 < 64; ++k4) {
        const float4 q = *reinterpret_cast<const float4*>(qrow + k4 * 4);
        const float4 v = *reinterpret_cast<const float4*>(krow + k4 * 4);
        acc = fmaf(q.x, v.x, acc);
        acc = fmaf(q.y, v.y, acc);
        acc = fmaf(q.z, v.z, acc);
        acc = fmaf(q.w, v.w, acc);
    }
    const float myv = (lane < RK) ? acc : -3.0e38f;
    const int myidx = (lane < RK) ? cidx : 0x7FFFFFFF;

    int rank = 0;
    for (int j = 0; j < RK; ++j) {
        const float vj = __shfl(myv, j);
        const int ij = __shfl(myidx, j);
        rank += ((vj > myv) || (vj == myv && ij < myidx)) ? 1 : 0;
    }
    float mx = myv;
    #pragma unroll
    for (int off = 32; off >= 1; off >>= 1) mx = fmaxf(mx, __shfl_xor(mx, off));
    const float e = (rank < TOPK && lane < RK) ? expf(myv - mx) : 0.f;
    float ssum = e;
    #pragma unroll
    for (int off = 32; off >= 1; off >>= 1) ssum += __shfl_xor(ssum, off);
    if (rank < TOPK && lane < RK) {
        wsoft[(size_t)row * TOPK + rank] = e / ssum;
        widx[(size_t)row * TOPK + rank] = myidx;
    }
}

// =======================================================================
// Kernel D: gather feat + weighted sum, transposed store to [b][c][n]
// =======================================================================
__global__ __launch_bounds__(256) void k_out(const unsigned short* __restrict__ feat,
                                             const float* __restrict__ wsoft,
                                             const int* __restrict__ widx,
                                             float* __restrict__ out) {
    __shared__ float wts[32][16];
    __shared__ int ids[32][16];
    __shared__ float tmp[32][257];
    const int nb = blockIdx.x;
    const int b = blockIdx.y;
    const int n0 = nb * 32;
    const int tid = threadIdx.x;
    if (tid < 32) {
        const size_t row = (size_t)b * NTOK + n0 + tid;
        #pragma unroll
        for (int k = 0; k < 16; ++k) {
            wts[tid][k] = wsoft[row * 16 + k];
            ids[tid][k] = widx[row * 16 + k];
        }
    }
    __syncthreads();
    const unsigned short* featb = feat + (size_t)b * NTOK * CH;
    const int c = tid;
    for (int n = 0; n < 32; ++n) {
        float a = 0.f;
        #pragma unroll
        for (int k = 0; k < 16; ++k)
            a = fmaf(wts[n][k], bf16_to_f32(featb[(size_t)ids[n][k] * CH + c]), a);
        tmp[n][c] = a;
    }
    __syncthreads();
    float* outb = out + (size_t)b * CH * NTOK + n0;
    #pragma unroll
    for (int ci = 0; ci < 32; ++ci) {
        const int cc = ci * 8 + (tid >> 5);
        const int nn = tid & 31;
        outb[(size_t)cc * NTOK + nn] = tmp[nn][cc];
    }
}

// =======================================================================
extern "C" void kernel_launch(void* const* d_in, const int* in_sizes, int n_in,
                              void* d_out, int out_size, void* d_ws, size_t ws_size,
                              hipStream_t stream) {
    (void)in_sizes; (void)n_in; (void)out_size; (void)ws_size;
    const float* x    = (const float*)d_in[0];
    const float* Wm   = (const float*)d_in[1];
    const float* bias = (const float*)d_in[2];
    float* out = (float*)d_out;

    char* ws = (char*)d_ws;
    // ws layout (bytes):
    //  pos    f32  [8][2304][256]   18,874,368   @ 0
    //  posbf  bf16 same              9,437,184   @ 18874368
    //  feat   bf16 same              9,437,184   @ 28311552
    //  Wt     f32  [256][512]          524,288   @ 37748736
    //  cand   i32  [18432][24]       1,769,472   @ 38273024
    //  wsoft  f32  [18432][16]       1,179,648   @ 40042496
    //  widx   i32  [18432][16]       1,179,648   @ 41222144
    float* pos            = (float*)(ws);
    unsigned short* posbf = (unsigned short*)(ws + 18874368);
    unsigned short* feat  = (unsigned short*)(ws + 28311552);
    float* Wt             = (float*)(ws + 37748736);
    int* cand             = (int*)(ws + 38273024);
    float* wsoft          = (float*)(ws + 40042496);
    int* widx             = (int*)(ws + 41222144);

    k_wt<<<dim3(8, 16), 256, 0, stream>>>(Wm, Wt);
    k_gemm1<<<dim3(4, 36, 8), 256, 0, stream>>>(x, Wt, bias, feat, pos);
    k_norm<<<dim3(4608), 256, 0, stream>>>(pos, posbf);
    k_simsel<<<dim3(72, 8), 256, 0, stream>>>(posbf, cand);
    k_rescore<<<dim3(4608), 256, 0, stream>>>(pos, cand, wsoft, widx);
    k_out<<<dim3(72, 8), 256, 0, stream>>>(feat, wsoft, widx, out);
}